// Round 12
// baseline (8511.206 us; speedup 1.0000x reference)
//
#include <hip/hip_runtime.h>
#include <hip/hip_fp16.h>
#include <math.h>

#define N_T 16384
#define S   128
#define S3  384
#define THREADS 512          // 8 waves, 2 per SIMD
#define L2E 1.4426950408889634f

// native 2^x / 1/x where available; exact fallbacks keep compilation safe
#if __has_builtin(__builtin_amdgcn_exp2f)
#define EXP2(x) __builtin_amdgcn_exp2f(x)
#else
#define EXP2(x) exp2f(x)
#endif
#if __has_builtin(__builtin_amdgcn_rcpf)
#define RCP(x) __builtin_amdgcn_rcpf(x)
#else
#define RCP(x) (1.0f / (x))
#endif

// raw barrier: LDS-visibility only (NO vmcnt drain -> in-flight global loads
// can cross barriers freely, unlike __syncthreads()).
#define BAR() do { \
    asm volatile("s_waitcnt lgkmcnt(0)" ::: "memory"); \
    __builtin_amdgcn_s_barrier();                      \
    asm volatile("" ::: "memory");                     \
} while (0)

// ---------------------------------------------------------------------------
// Kernel 0: fold proj into w_ih (fp32). Fold b_ih fully and the r/z parts of
// b_hh (linear inside the sigmoid args); the n-part of b_hh is scaled by r
// and stays separate. gi columns carry the exp2 prescale IN FP32: log2e for
// r/z rows, 2*log2e for n rows (tanh(x) = 1 - 2/(2^(2*log2e*x)+1)).
// ---------------------------------------------------------------------------
__global__ void prep_kernel(const float* __restrict__ w_ih,
                            const float* __restrict__ b_ih,
                            const float* __restrict__ b_hh,
                            const float* __restrict__ proj_w,
                            const float* __restrict__ proj_b,
                            float* __restrict__ Mt,
                            float* __restrict__ b2,
                            float* __restrict__ mc) {
    int j = blockIdx.x;    // 0..383
    int m = threadIdx.x;   // 0..127
    const float sc = (j < 2 * S) ? L2E : 2.f * L2E;
    float acc = 0.f;
    for (int k = 0; k < S - 1; ++k)
        acc += w_ih[j * S + k] * proj_w[k * S + m];
    Mt[m * S3 + j] = acc * sc;
    if (m == 0) {
        float a = 0.f;
        for (int k = 0; k < S - 1; ++k) a += w_ih[j * S + k] * proj_b[k];
        b2[j] = (b_ih[j] + ((j < 2 * S) ? b_hh[j] : 0.f) + a) * sc;
        mc[j] = w_ih[j * S + (S - 1)] * sc;
    }
}

// ---------------------------------------------------------------------------
// Kernel 0b: w_hh as packed f16 pairs, CONTIGUOUS pairing, UNSCALED (exact
// R7/R10 weight realization; log2e applied at runtime via one fma per gate).
// ---------------------------------------------------------------------------
__global__ void wcvt_kernel(const float* __restrict__ w_hh,
                            unsigned* __restrict__ Whh16) {
    int j = blockIdx.x;    // row 0..383
    int m = threadIdx.x;   // word 0..63
    __half2 p = __floats2half2_rn(w_hh[j * S + 2 * m], w_hh[j * S + 2 * m + 1]);
    Whh16[j * 64 + m] = *(unsigned*)&p;
}

// ---------------------------------------------------------------------------
// Kernel 1: gi[t][j] = b2[j] + dot(evs[t], M[j]) + (t==0 ? mc[j] : 0)  (fp32)
// (columns already carry the fp32 exp2 prescale via Mt/b2/mc)
// ---------------------------------------------------------------------------
#define TB 32
__global__ void gi_kernel(const float* __restrict__ evs,
                          const float* __restrict__ Mt,
                          const float* __restrict__ b2,
                          const float* __restrict__ mc,
                          float* __restrict__ gi) {
    int j  = threadIdx.x;        // 0..383
    int t0 = blockIdx.x * TB;

    float mcol[S];
#pragma unroll
    for (int k = 0; k < S; ++k) mcol[k] = Mt[k * S3 + j];

    __shared__ float ev[TB][S];
    for (int i = j; i < TB * S; i += S3)
        ev[i / S][i % S] = evs[t0 * S + i];
    __syncthreads();

    float bb  = b2[j];
    float mcj = mc[j];
    for (int tt = 0; tt < TB; ++tt) {
        int t = t0 + tt;
        float acc = bb + ((t == 0) ? mcj : 0.f);
#pragma unroll
        for (int k = 0; k < S; ++k) acc += ev[tt][k] * mcol[k];
        gi[t * S3 + j] = acc;
    }
}

// ---------------------------------------------------------------------------
// Kernel 2: sequential GRU scan. 1 workgroup, 512 threads = 8 waves (2/SIMD).
//
// R12 = cross-wave latency overlap. Bisection verdict from R8/R9/R11: the
// multi-sub-accumulator asm-dot pattern miscompiles (3/3 failures); R10's
// sequential 3-accumulator idiom passes (2/2). So per-wave scheduling is
// frozen at the R10 idiom; the remaining ~600cy/step stall (h16 read, shfl,
// gate chain, barrier) is instead OVERLAPPED ACROSS WAVES: 2 waves/SIMD,
// each with HALF the dots (48), so per-SIMD issue is unchanged while one
// wave's stall phases fill with the other wave's issue.
//   wave c = 0..7 owns gate rows Rh = 16c + (l&15); lane quarter kq = l>>4
//   takes k-words [16kq, 16kq+16). 48 dot2/lane (3 rows x 16 words),
//   sequential a0/a1/a2 accumulators (R10 idiom, stride-3 interleave).
//   Combine: 2-stage shfl_xor (16 then 32), issued after all dots (R10
//   placement), 3 gates pipelined per stage. Gate computed 4x-redundant
//   across quarters; quarter 0 (l<16) writes h16. One BAR/step, h16
//   double-buffered by step parity. gi depth-4 register pipeline unchanged.
// ---------------------------------------------------------------------------
#define DOT2(acc, wreg, hreg_) \
    asm("v_dot2_f32_f16 %0, %1, %2, %0" : "+v"(acc) : "v"(wreg), "v"(hreg_));

__global__ __attribute__((amdgpu_flat_work_group_size(THREADS, THREADS),
                          amdgpu_waves_per_eu(2, 2))) void
scan_kernel(const float* __restrict__ gi,
            const unsigned* __restrict__ Whh16,
            const float* __restrict__ h0,
            const float* __restrict__ b_hh,
            const float* __restrict__ final_w,
            const float* __restrict__ final_b,
            float* __restrict__ out) {
    const int tid = threadIdx.x;
    const int l   = tid & 63;
    const int c   = tid >> 6;           // wave 0..7
    const int Rh  = (c << 4) + (l & 15);// gate row 0..127 owned by this lane
    const int kq  = l >> 4;             // k-quarter 0..3
    const int kw0 = kq << 4;            // first k-word of this lane's quarter

    // weights: rows Rh, Rh+128, Rh+256; words [kw0, kw0+16)
    unsigned w0[16], w1[16], w2[16];
    {
        const unsigned* pw = Whh16 + (size_t)Rh * 64 + kw0;
#pragma unroll
        for (int i = 0; i < 16; ++i) {
            w0[i] = pw[i];
            w1[i] = pw[i + 128 * 64];
            w2[i] = pw[i + 256 * 64];
        }
    }

    __shared__ __align__(16) unsigned h16[2][64];   // (h[2i],h[2i+1]) pairs
    __shared__ float hfin[S];

    // n-gate bias (scaled by r at runtime; carries the 2*log2e factor, fp32)
    float bn2 = b_hh[2 * S + Rh] * (2.f * L2E);

    float hreg = h0[Rh];
    if (l < 16)
        ((unsigned short*)&h16[0][0])[Rh] =
            __half_as_ushort(__float2half(hreg));

    // gi register pipeline, depth 4 (slot u used at steps t == u mod 4)
    float gpr[4], gpz[4], gpn[4];
#pragma unroll
    for (int u = 0; u < 4; ++u) {
        gpr[u] = gi[(size_t)u * S3 + Rh];
        gpz[u] = gi[(size_t)u * S3 + Rh + S];
        gpn[u] = gi[(size_t)u * S3 + Rh + 2 * S];
    }
    BAR();   // h16[0] visible

    for (int t = 0; t < N_T; t += 4) {
#pragma unroll
        for (int u = 0; u < 4; ++u) {
            const int tt = t + u;
            // h k-quarter: 4 ds_read_b128 (uniform addr per quarter-wave)
            const uint4* hp = (const uint4*)&h16[u & 1][kw0];
            uint4 q[4];
#pragma unroll
            for (int i = 0; i < 4; ++i) q[i] = hp[i];

            float a0 = 0.f, a1 = 0.f, a2 = 0.f;
#pragma unroll
            for (int i = 0; i < 4; ++i) {
                const unsigned hw[4] = { q[i].x, q[i].y, q[i].z, q[i].w };
#pragma unroll
                for (int jj = 0; jj < 4; ++jj) {
                    const int idx = 4 * i + jj;
                    DOT2(a0, w0[idx], hw[jj])
                    DOT2(a1, w1[idx], hw[jj])
                    DOT2(a2, w2[idx], hw[jj])
                }
            }
            // combine k-quarters: 2-stage shfl_xor (standard primitive),
            // 3 gates pipelined per stage (R10 placement: after all dots)
            a0 += __shfl_xor(a0, 16, 64);
            a1 += __shfl_xor(a1, 16, 64);
            a2 += __shfl_xor(a2, 16, 64);
            a0 += __shfl_xor(a0, 32, 64);
            a1 += __shfl_xor(a1, 32, 64);
            a2 += __shfl_xor(a2, 32, 64);

            // gates: sigmoid/tanh via native 2^x and v_rcp_f32 (verified R10)
            float r  = RCP(1.f + EXP2(-__builtin_fmaf(L2E, a0, gpr[u])));
            float z  = RCP(1.f + EXP2(-__builtin_fmaf(L2E, a1, gpz[u])));
            float e  = EXP2(__builtin_fmaf(
                           r, __builtin_fmaf(2.f * L2E, a2, bn2), gpn[u]));
            float n  = 1.f - 2.f * RCP(e + 1.f);   // tanh
            hreg = n + z * (hreg - n);

            if (l < 16)
                ((unsigned short*)&h16[(u & 1) ^ 1][0])[Rh] =
                    __half_as_ushort(__float2half(hreg));

            // refill this gi slot for step tt+4 (vmem, flies across BAR)
            if (tt + 4 < N_T) {
                gpr[u] = gi[(size_t)(tt + 4) * S3 + Rh];
                gpz[u] = gi[(size_t)(tt + 4) * S3 + Rh + S];
                gpn[u] = gi[(size_t)(tt + 4) * S3 + Rh + 2 * S];
            }

            BAR();   // new h16 visible; old buffer now safe to overwrite
        }
    }

    // publish fp32 h (owner lanes only), then out = h @ final_w.T + final_b
    if (l < 16) hfin[Rh] = hreg;
    BAR();
    if (tid < 3) {
        float acc = final_b[tid];
        for (int k = 0; k < S; ++k) acc += final_w[tid * S + k] * hfin[k];
        out[tid] = acc;
    }
}

// ---------------------------------------------------------------------------
extern "C" void kernel_launch(void* const* d_in, const int* in_sizes, int n_in,
                              void* d_out, int out_size, void* d_ws, size_t ws_size,
                              hipStream_t stream) {
    const float* evs     = (const float*)d_in[0];
    const float* h0      = (const float*)d_in[1];
    const float* w_ih    = (const float*)d_in[2];
    const float* w_hh    = (const float*)d_in[3];
    const float* b_ih    = (const float*)d_in[4];
    const float* b_hh    = (const float*)d_in[5];
    const float* proj_w  = (const float*)d_in[6];
    const float* proj_b  = (const float*)d_in[7];
    const float* final_w = (const float*)d_in[8];
    const float* final_b = (const float*)d_in[9];
    float* out = (float*)d_out;

    // workspace layout (floats)
    float* gi = (float*)d_ws;                  // N_T * 384
    float* Mt = gi + (size_t)N_T * S3;         // 128 * 384
    float* b2 = Mt + (size_t)S * S3;           // 384
    float* mc = b2 + S3;                       // 384
    unsigned* Whh16 = (unsigned*)(mc + S3);    // 384 * 64 packed f16 pairs

    prep_kernel<<<S3, S, 0, stream>>>(w_ih, b_ih, b_hh, proj_w, proj_b, Mt, b2, mc);
    wcvt_kernel<<<S3, 64, 0, stream>>>(w_hh, Whh16);
    gi_kernel<<<N_T / TB, S3, 0, stream>>>(evs, Mt, b2, mc, gi);
    scan_kernel<<<1, THREADS, 0, stream>>>(gi, Whh16, h0, b_hh,
                                           final_w, final_b, out);
}

// Round 13
// 6695.397 us; speedup vs baseline: 1.2712x; 1.2712x over previous
//
#include <hip/hip_runtime.h>
#include <hip/hip_fp16.h>
#include <math.h>

#define N_T 16384
#define S   128
#define S3  384
#define THREADS 256          // 4 waves, 1 per SIMD
#define L2E 1.4426950408889634f

typedef _Float16 half8 __attribute__((ext_vector_type(8)));
typedef float    f32x4 __attribute__((ext_vector_type(4)));

// native 2^x / 1/x where available; exact fallbacks keep compilation safe
#if __has_builtin(__builtin_amdgcn_exp2f)
#define EXP2(x) __builtin_amdgcn_exp2f(x)
#else
#define EXP2(x) exp2f(x)
#endif
#if __has_builtin(__builtin_amdgcn_rcpf)
#define RCP(x) __builtin_amdgcn_rcpf(x)
#else
#define RCP(x) (1.0f / (x))
#endif

// raw barrier: LDS-visibility only (NO vmcnt drain -> in-flight global loads
// can cross barriers freely, unlike __syncthreads()).
#define BAR() do { \
    asm volatile("s_waitcnt lgkmcnt(0)" ::: "memory"); \
    __builtin_amdgcn_s_barrier();                      \
    asm volatile("" ::: "memory");                     \
} while (0)

// ---------------------------------------------------------------------------
// Kernel 0: fold proj into w_ih (fp32). b_ih + r/z parts of b_hh folded;
// n-part of b_hh stays separate (scaled by r). gi columns carry the exp2
// prescale IN FP32: log2e (r,z rows), 2*log2e (n rows).
// ---------------------------------------------------------------------------
__global__ void prep_kernel(const float* __restrict__ w_ih,
                            const float* __restrict__ b_ih,
                            const float* __restrict__ b_hh,
                            const float* __restrict__ proj_w,
                            const float* __restrict__ proj_b,
                            float* __restrict__ Mt,
                            float* __restrict__ b2,
                            float* __restrict__ mc) {
    int j = blockIdx.x;    // 0..383
    int m = threadIdx.x;   // 0..127
    const float sc = (j < 2 * S) ? L2E : 2.f * L2E;
    float acc = 0.f;
    for (int k = 0; k < S - 1; ++k)
        acc += w_ih[j * S + k] * proj_w[k * S + m];
    Mt[m * S3 + j] = acc * sc;
    if (m == 0) {
        float a = 0.f;
        for (int k = 0; k < S - 1; ++k) a += w_ih[j * S + k] * proj_b[k];
        b2[j] = (b_ih[j] + ((j < 2 * S) ? b_hh[j] : 0.f) + a) * sc;
        mc[j] = w_ih[j * S + (S - 1)] * sc;
    }
}

// ---------------------------------------------------------------------------
// Kernel 0b: w_hh as packed f16 pairs, CONTIGUOUS pairing, UNSCALED (exact
// verified weight realization). Row j halves are linear: word i = (w[j][2i],
// w[j][2i+1]) -- serves both the dot2 path and the MFMA A-fragments.
// ---------------------------------------------------------------------------
__global__ void wcvt_kernel(const float* __restrict__ w_hh,
                            unsigned* __restrict__ Whh16) {
    int j = blockIdx.x;    // row 0..383
    int m = threadIdx.x;   // word 0..63
    __half2 p = __floats2half2_rn(w_hh[j * S + 2 * m], w_hh[j * S + 2 * m + 1]);
    Whh16[j * 64 + m] = *(unsigned*)&p;
}

// ---------------------------------------------------------------------------
// Kernel 1: gi[t][j] = b2[j] + dot(evs[t], M[j]) + (t==0 ? mc[j] : 0)  (fp32)
// ---------------------------------------------------------------------------
#define TB 32
__global__ void gi_kernel(const float* __restrict__ evs,
                          const float* __restrict__ Mt,
                          const float* __restrict__ b2,
                          const float* __restrict__ mc,
                          float* __restrict__ gi) {
    int j  = threadIdx.x;        // 0..383
    int t0 = blockIdx.x * TB;

    float mcol[S];
#pragma unroll
    for (int k = 0; k < S; ++k) mcol[k] = Mt[k * S3 + j];

    __shared__ float ev[TB][S];
    for (int i = j; i < TB * S; i += S3)
        ev[i / S][i % S] = evs[t0 * S + i];
    __syncthreads();

    float bb  = b2[j];
    float mcj = mc[j];
    for (int tt = 0; tt < TB; ++tt) {
        int t = t0 + tt;
        float acc = bb + ((t == 0) ? mcj : 0.f);
#pragma unroll
        for (int k = 0; k < S; ++k) acc += ev[tt][k] * mcol[k];
        gi[t * S3 + j] = acc;
    }
}

// ---------------------------------------------------------------------------
// Kernel 2: sequential GRU scan. 1 workgroup, 256 threads = 4 waves (1/SIMD).
//
// R13: replace the 96-dot2 (384cy issue) matvec with 24 chained MFMAs
// (~120cy issue) using BROADCAST-B: B[k][n] = h[k] for all n, so every C
// column holds identical gh -> B col-mapping irrelevant, no cross-lane
// combine, full-K row sums land in registers. Wave c owns rows
// {0,128,256}+32c..+31 as 6 C-tiles x 4 K-chunk MFMAs. Gate values reach
// owner lanes via a 7-cndmask register select (C is 16x duplicated across
// lanes). Same verified gate math / h16 double-buffer / 1 BAR per step /
// gi depth-4 pipeline as R10.
//
// Safety: pre-loop MFMA layout SELF-TEST (asymmetric A = 32r+k, B = delta
// at k=5; detects all harmful row/col/transpose mapping errors; benign
// consistent-k permutations cancel in a matvec by construction). If the
// test fails on this hardware/compiler, falls back to the VERBATIM verified
// R10 loop (uniform branch, same barrier discipline). Builtins only -- no
// inline-asm accumulator webs (the R8/R9/R11 miscompile class).
// ---------------------------------------------------------------------------
#define DOT2(acc, wreg, hreg_) \
    asm("v_dot2_f32_f16 %0, %1, %2, %0" : "+v"(acc) : "+v"(wreg) ? 0 : 0);
#undef DOT2
#define DOT2(acc, wreg, hreg_) \
    asm("v_dot2_f32_f16 %0, %1, %2, %0" : "+v"(acc) : "v"(wreg), "v"(hreg_));

__global__ __attribute__((amdgpu_flat_work_group_size(THREADS, THREADS),
                          amdgpu_waves_per_eu(1, 1))) void
scan_kernel(const float* __restrict__ gi,
            const unsigned* __restrict__ Whh16,
            const float* __restrict__ h0,
            const float* __restrict__ b_hh,
            const float* __restrict__ final_w,
            const float* __restrict__ final_b,
            float* __restrict__ out) {
    const int tid = threadIdx.x;
    const int l   = tid & 63;
    const int c   = tid >> 6;           // wave 0..3

    __shared__ __align__(16) unsigned h16[2][64];   // (h[2i],h[2i+1]) pairs
    __shared__ float hfin[S];

    // ---- MFMA layout self-test (registers only; block-uniform verdict) ----
    // Assumed: A row = l&15, A k = 8*(l>>4)+i ; B k = 8*(l>>4)+i ;
    //          C col = l&15, C row = (l>>4)*4 + reg.
    bool usemfma;
    {
        const int g4 = l >> 4;
        half8 ta, tb;
#pragma unroll
        for (int i = 0; i < 8; ++i) {
            int k = 8 * g4 + i;
            ta[i] = (_Float16)(float)((l & 15) * 32 + k);
            tb[i] = (k == 5) ? (_Float16)1.f : (_Float16)0.f;
        }
        f32x4 tc = {0.f, 0.f, 0.f, 0.f};
        tc = __builtin_amdgcn_mfma_f32_16x16x32_f16(ta, tb, tc, 0, 0, 0);
        bool ok = true;
#pragma unroll
        for (int rg = 0; rg < 4; ++rg)
            ok = ok && (tc[rg] == (float)((4 * g4 + rg) * 32 + 5));
        usemfma = (bool)__all((int)ok);
    }

    if (usemfma) {
        // ================= MFMA path =================
        const int g4 = l >> 4;              // lane 16-group
        const int p  = l & 7;               // gate-row selector
        const int jj = 4 * g4 + (p & 3) + ((p & 4) ? 16 : 0);
        const int rr = (c << 5) + jj;       // owned gate row 0..127
        const bool writer = (l & 15) < 8;   // one writer per row
        const bool s0 = (p & 1) != 0, s1 = (p & 2) != 0, s2 = (p & 4) != 0;

        // A fragments: tile m = [r-lo,r-hi,z-lo,z-hi,n-lo,n-hi], K-chunk q.
        // A[row][k]: row = l&15 (tile-local), k = 8*g4 + i  ->  halves at
        // word 16q + 4*g4 of W row j = 128*(m>>1) + 32c + 16*(m&1) + (l&15).
        half8 a[6][4];
#pragma unroll
        for (int m = 0; m < 6; ++m) {
            const int j = 128 * (m >> 1) + 32 * c + 16 * (m & 1) + (l & 15);
            const unsigned* rowp = Whh16 + (size_t)j * 64 + 4 * g4;
#pragma unroll
            for (int q = 0; q < 4; ++q)
                a[m][q] = *(const half8*)(rowp + 16 * q);
        }

        float bn2  = b_hh[2 * S + rr] * (2.f * L2E);
        float hreg = h0[rr];
        if (writer)
            ((unsigned short*)&h16[0][0])[rr] =
                __half_as_ushort(__float2half(hreg));

        float gpr[4], gpz[4], gpn[4];
#pragma unroll
        for (int u = 0; u < 4; ++u) {
            gpr[u] = gi[(size_t)u * S3 + rr];
            gpz[u] = gi[(size_t)u * S3 + rr + S];
            gpn[u] = gi[(size_t)u * S3 + rr + 2 * S];
        }
        BAR();   // h16[0] visible

        for (int t = 0; t < N_T; t += 4) {
#pragma unroll
            for (int u = 0; u < 4; ++u) {
                const int tt = t + u;
                // broadcast-B: lane half i = h[32q + 8*g4 + i]
                //   -> half8 index 4q + g4 into the 64-word h image
                const half8* hb = (const half8*)&h16[u & 1][0];
                half8 b[4];
#pragma unroll
                for (int q = 0; q < 4; ++q) b[q] = hb[4 * q + g4];

                f32x4 cc[6];
#pragma unroll
                for (int m = 0; m < 6; ++m) cc[m] = (f32x4){0.f, 0.f, 0.f, 0.f};
#pragma unroll
                for (int q = 0; q < 4; ++q)
#pragma unroll
                    for (int m = 0; m < 6; ++m)
                        cc[m] = __builtin_amdgcn_mfma_f32_16x16x32_f16(
                                    a[m][q], b[q], cc[m], 0, 0, 0);

                // register select: row jj -> tile half (s2), reg (s0,s1)
                f32x4 t0v = s2 ? cc[1] : cc[0];
                f32x4 t1v = s2 ? cc[3] : cc[2];
                f32x4 t2v = s2 ? cc[5] : cc[4];
                float a0 = s1 ? (s0 ? t0v.w : t0v.z) : (s0 ? t0v.y : t0v.x);
                float a1 = s1 ? (s0 ? t1v.w : t1v.z) : (s0 ? t1v.y : t1v.x);
                float a2 = s1 ? (s0 ? t2v.w : t2v.z) : (s0 ? t2v.y : t2v.x);

                // gates: verified R10 math (native 2^x, v_rcp)
                float r  = RCP(1.f + EXP2(-__builtin_fmaf(L2E, a0, gpr[u])));
                float z  = RCP(1.f + EXP2(-__builtin_fmaf(L2E, a1, gpz[u])));
                float e  = EXP2(__builtin_fmaf(
                               r, __builtin_fmaf(2.f * L2E, a2, bn2), gpn[u]));
                float n  = 1.f - 2.f * RCP(e + 1.f);   // tanh
                hreg = n + z * (hreg - n);

                if (writer)
                    ((unsigned short*)&h16[(u & 1) ^ 1][0])[rr] =
                        __half_as_ushort(__float2half(hreg));

                if (tt + 4 < N_T) {
                    gpr[u] = gi[(size_t)(tt + 4) * S3 + rr];
                    gpz[u] = gi[(size_t)(tt + 4) * S3 + rr + S];
                    gpn[u] = gi[(size_t)(tt + 4) * S3 + rr + 2 * S];
                }

                BAR();
            }
        }
        if (writer) hfin[rr] = hreg;
    } else {
        // ================= fallback: VERBATIM verified R10 loop =============
        const int lh  = l & 31;
        const int Rh  = (c << 5) + lh;
        const int kw0 = (l & 32);

        unsigned w0[32], w1[32], w2[32];
        {
            const unsigned* pw = Whh16 + (size_t)Rh * 64 + kw0;
#pragma unroll
            for (int i = 0; i < 32; ++i) {
                w0[i] = pw[i];
                w1[i] = pw[i + 128 * 64];
                w2[i] = pw[i + 256 * 64];
            }
        }

        float bn2  = b_hh[2 * S + Rh] * (2.f * L2E);
        float hreg = h0[Rh];
        if (l < 32)
            ((unsigned short*)&h16[0][0])[Rh] =
                __half_as_ushort(__float2half(hreg));

        float gpr[4], gpz[4], gpn[4];
#pragma unroll
        for (int u = 0; u < 4; ++u) {
            gpr[u] = gi[(size_t)u * S3 + Rh];
            gpz[u] = gi[(size_t)u * S3 + Rh + S];
            gpn[u] = gi[(size_t)u * S3 + Rh + 2 * S];
        }
        BAR();

        for (int t = 0; t < N_T; t += 4) {
#pragma unroll
            for (int u = 0; u < 4; ++u) {
                const int tt = t + u;
                const uint4* hp = (const uint4*)&h16[u & 1][kw0];
                uint4 q[8];
#pragma unroll
                for (int i = 0; i < 8; ++i) q[i] = hp[i];

                float a0 = 0.f, a1 = 0.f, a2 = 0.f;
#pragma unroll
                for (int i = 0; i < 8; ++i) {
                    const unsigned hw[4] = { q[i].x, q[i].y, q[i].z, q[i].w };
#pragma unroll
                    for (int jj2 = 0; jj2 < 4; ++jj2) {
                        const int idx = 4 * i + jj2;
                        DOT2(a0, w0[idx], hw[jj2])
                        DOT2(a1, w1[idx], hw[jj2])
                        DOT2(a2, w2[idx], hw[jj2])
                    }
                }
                a0 += __shfl_xor(a0, 32, 64);
                a1 += __shfl_xor(a1, 32, 64);
                a2 += __shfl_xor(a2, 32, 64);

                float r  = RCP(1.f + EXP2(-__builtin_fmaf(L2E, a0, gpr[u])));
                float z  = RCP(1.f + EXP2(-__builtin_fmaf(L2E, a1, gpz[u])));
                float e  = EXP2(__builtin_fmaf(
                               r, __builtin_fmaf(2.f * L2E, a2, bn2), gpn[u]));
                float n  = 1.f - 2.f * RCP(e + 1.f);
                hreg = n + z * (hreg - n);

                if (l < 32)
                    ((unsigned short*)&h16[(u & 1) ^ 1][0])[Rh] =
                        __half_as_ushort(__float2half(hreg));

                if (tt + 4 < N_T) {
                    gpr[u] = gi[(size_t)(tt + 4) * S3 + Rh];
                    gpz[u] = gi[(size_t)(tt + 4) * S3 + Rh + S];
                    gpn[u] = gi[(size_t)(tt + 4) * S3 + Rh + 2 * S];
                }

                BAR();
            }
        }
        if (l < 32) hfin[Rh] = hreg;
    }

    // common epilogue: out = h @ final_w.T + final_b
    BAR();
    if (tid < 3) {
        float acc = final_b[tid];
        for (int k = 0; k < S; ++k) acc += final_w[tid * S + k] * hfin[k];
        out[tid] = acc;
    }
}

// ---------------------------------------------------------------------------
extern "C" void kernel_launch(void* const* d_in, const int* in_sizes, int n_in,
                              void* d_out, int out_size, void* d_ws, size_t ws_size,
                              hipStream_t stream) {
    const float* evs     = (const float*)d_in[0];
    const float* h0      = (const float*)d_in[1];
    const float* w_ih    = (const float*)d_in[2];
    const float* w_hh    = (const float*)d_in[3];
    const float* b_ih    = (const float*)d_in[4];
    const float* b_hh    = (const float*)d_in[5];
    const float* proj_w  = (const float*)d_in[6];
    const float* proj_b  = (const float*)d_in[7];
    const float* final_w = (const float*)d_in[8];
    const float* final_b = (const float*)d_in[9];
    float* out = (float*)d_out;

    // workspace layout (floats)
    float* gi = (float*)d_ws;                  // N_T * 384
    float* Mt = gi + (size_t)N_T * S3;         // 128 * 384
    float* b2 = Mt + (size_t)S * S3;           // 384
    float* mc = b2 + S3;                       // 384
    unsigned* Whh16 = (unsigned*)(mc + S3);    // 384 * 64 packed f16 pairs

    prep_kernel<<<S3, S, 0, stream>>>(w_ih, b_ih, b_hh, proj_w, proj_b, Mt, b2, mc);
    wcvt_kernel<<<S3, 64, 0, stream>>>(w_hh, Whh16);
    gi_kernel<<<N_T / TB, S3, 0, stream>>>(evs, Mt, b2, mc, gi);
    scan_kernel<<<1, THREADS, 0, stream>>>(gi, Whh16, h0, b_hh,
                                           final_w, final_b, out);
}